// Round 2
// baseline (582.360 us; speedup 1.0000x reference)
//
#include <hip/hip_runtime.h>

// CombineUV: out[b,s] = <input[b,:]*sig(alpha), W[l,:]> + <input[b,:]*sig(beta), V[l,:]> + bias[l]
// with l = shortlist[b,s]. L=131072, D=512, B=512, S=512.
//
// R3: INVERTED GATHER. R2 proved the kernel is bound by the random-2KB-row
// gather pattern itself (restructuring waves/shuffles changed nothing;
// 2.57 TB/s regardless). So: build an inverted index (l -> list of (b,s)),
// then STREAM weight/labels sequentially exactly once, reading the pre-gated
// input rows (ga/gb, 2 MB total) from workspace -- they fit in each XCD's
// 4 MB L2. Random HBM gather becomes sequential HBM stream + L2-resident
// random reads.
//
// Pipeline (all on one stream, order guarantees correctness):
//   1. gates:  ga/gb = input * sig(alpha/beta)  (+ zero counts)
//   2. hist:   counts[l] += 1 per shortlist entry
//   3. scan1/2/3: exclusive prefix sum starts[] (+ cursor copy)
//   4. fill:   idx[atomic cursor] = (b<<9)|s
//   5. main:   per row l: load W[l],V[l] (sequential, coalesced);
//              per ref: read ga[b],gb[b] (L2), dot, butterfly, scatter out.
//
// Workspace: 5 MB. NOTE: shortlist arrives as int32 (int64 read faulted in R1).

#define L_DIM 131072
#define D_DIM 512
#define B_DIM 512
#define S_DIM 512
#define NREF  (B_DIM * S_DIM)   // 262144

// ---- workspace layout (byte offsets) ----
#define WS_GA     0                       // [B,D] f32, 1 MB
#define WS_GB     (1u << 20)              // 1 MB
#define WS_COUNTS (2u << 20)              // [L] i32, 512 KB
#define WS_STARTS ((2u << 20) + (512u << 10))
#define WS_CURSOR (3u << 20)
#define WS_BSUM   ((3u << 20) + (512u << 10))          // [512] i32
#define WS_BOFF   ((3u << 20) + (512u << 10) + 4096)   // [512] i32
#define WS_IDX    (4u << 20)              // [NREF] u32, 1 MB
// total: 5 MB

// 1) gated input rows + zero counts. grid 512 x 256.
__global__ void gates_kernel(const float* __restrict__ input,
                             const float* __restrict__ alpha,
                             const float* __restrict__ beta,
                             float* __restrict__ ga, float* __restrict__ gb,
                             int* __restrict__ counts) {
    const int b = blockIdx.x, tid = threadIdx.x;
    for (int d = tid; d < D_DIM; d += 256) {
        const float x  = input[b * D_DIM + d];
        const float sa = 1.0f / (1.0f + __expf(-alpha[d]));
        const float sb = 1.0f / (1.0f + __expf(-beta[d]));
        ga[b * D_DIM + d] = x * sa;
        gb[b * D_DIM + d] = x * sb;
    }
    counts[b * 256 + tid] = 0;   // 512*256 == L_DIM exactly
}

// 2) histogram. grid 1024 x 256.
__global__ void hist_kernel(const int* __restrict__ shortlist, int* __restrict__ counts) {
    const int i = blockIdx.x * 256 + threadIdx.x;
    atomicAdd(&counts[shortlist[i]], 1);
}

// 3a) per-256-chunk sums. grid 512 x 256.
__global__ void scan1_kernel(const int* __restrict__ counts, int* __restrict__ bsum) {
    __shared__ int s[256];
    const int tid = threadIdx.x;
    s[tid] = counts[blockIdx.x * 256 + tid];
    __syncthreads();
    for (int off = 128; off > 0; off >>= 1) {
        if (tid < off) s[tid] += s[tid + off];
        __syncthreads();
    }
    if (tid == 0) bsum[blockIdx.x] = s[0];
}

// 3b) exclusive scan of the 512 chunk sums. 1 block x 512.
__global__ void scan2_kernel(const int* __restrict__ bsum, int* __restrict__ boff) {
    __shared__ int s[512];
    const int tid = threadIdx.x;
    const int own = bsum[tid];
    s[tid] = own;
    __syncthreads();
    for (int off = 1; off < 512; off <<= 1) {
        const int v = (tid >= off) ? s[tid - off] : 0;
        __syncthreads();
        s[tid] += v;
        __syncthreads();
    }
    boff[tid] = s[tid] - own;   // exclusive
}

// 3c) within-chunk exclusive scan + chunk offset -> starts, cursor. grid 512 x 256.
__global__ void scan3_kernel(const int* __restrict__ counts, const int* __restrict__ boff,
                             int* __restrict__ starts, int* __restrict__ cursor) {
    __shared__ int s[256];
    const int tid = threadIdx.x;
    const int i   = blockIdx.x * 256 + tid;
    const int own = counts[i];
    s[tid] = own;
    __syncthreads();
    for (int off = 1; off < 256; off <<= 1) {
        const int v = (tid >= off) ? s[tid - off] : 0;
        __syncthreads();
        s[tid] += v;
        __syncthreads();
    }
    const int st = boff[blockIdx.x] + s[tid] - own;
    starts[i] = st;
    cursor[i] = st;
}

// 4) scatter-fill inverted index. grid 1024 x 256.
__global__ void fill_kernel(const int* __restrict__ shortlist, int* __restrict__ cursor,
                            unsigned* __restrict__ idx) {
    const int i = blockIdx.x * 256 + threadIdx.x;   // i = b*512 + s
    const int l = shortlist[i];
    const int pos = atomicAdd(&cursor[l], 1);
    idx[pos] = (unsigned)i;                          // (b<<9)|s
}

// 5) main: stream rows, L2-resident gate reads. grid 2048 x 256 (4 waves).
__global__ __launch_bounds__(256)
void main_kernel(const float* __restrict__ weight, const float* __restrict__ labels,
                 const float* __restrict__ bias,
                 const float* __restrict__ ga, const float* __restrict__ gb,
                 const int* __restrict__ starts, const int* __restrict__ counts,
                 const unsigned* __restrict__ idx, float* __restrict__ out) {
    const int wave = threadIdx.x >> 6;
    const int lane = threadIdx.x & 63;
    const int row0 = (blockIdx.x * 4 + wave) * 16;   // 16 consecutive rows per wave

    const float4* __restrict__ Wf = (const float4*)weight;
    const float4* __restrict__ Vf = (const float4*)labels;
    const float4* __restrict__ GA = (const float4*)ga;
    const float4* __restrict__ GB = (const float4*)gb;

    for (int r = 0; r < 16; ++r) {
        const int l = row0 + r;
        const int n = counts[l];          // wave-uniform
        if (n == 0) continue;             // skip unreferenced rows (13.5%)
        const int   st = starts[l];
        const float bl = bias[l];

        // lane owns 8 contiguous floats of each row
        const int base = l * 128 + lane * 2;
        const float4 w0 = Wf[base], w1 = Wf[base + 1];
        const float4 v0 = Vf[base], v1 = Vf[base + 1];

        for (int j = 0; j < n; ++j) {
            const unsigned e = idx[st + j];           // wave-uniform
            const int bb = (int)(e >> 9);
            const int ss = (int)(e & 511u);
            const int gbase = bb * 128 + lane * 2;    // whole wave reads one 2KB row (L2-hot)
            const float4 A0 = GA[gbase], A1 = GA[gbase + 1];
            const float4 B0 = GB[gbase], B1 = GB[gbase + 1];

            float acc = w0.x * A0.x + w0.y * A0.y + w0.z * A0.z + w0.w * A0.w
                      + w1.x * A1.x + w1.y * A1.y + w1.z * A1.z + w1.w * A1.w
                      + v0.x * B0.x + v0.y * B0.y + v0.z * B0.z + v0.w * B0.w
                      + v1.x * B1.x + v1.y * B1.y + v1.z * B1.z + v1.w * B1.w;

            #pragma unroll
            for (int off = 32; off > 0; off >>= 1)
                acc += __shfl_xor(acc, off, 64);

            if (lane == 0) out[bb * S_DIM + ss] = acc + bl;
        }
    }
}

extern "C" void kernel_launch(void* const* d_in, const int* in_sizes, int n_in,
                              void* d_out, int out_size, void* d_ws, size_t ws_size,
                              hipStream_t stream) {
    const float* input     = (const float*)d_in[0];
    const float* labels    = (const float*)d_in[1];
    const float* weight    = (const float*)d_in[2];
    const float* alpha     = (const float*)d_in[3];
    const float* beta      = (const float*)d_in[4];
    const float* bias      = (const float*)d_in[5];
    const int* shortlist   = (const int*)d_in[6];
    float* out             = (float*)d_out;

    char* ws = (char*)d_ws;
    float*    ga     = (float*)(ws + WS_GA);
    float*    gb     = (float*)(ws + WS_GB);
    int*      counts = (int*)(ws + WS_COUNTS);
    int*      starts = (int*)(ws + WS_STARTS);
    int*      cursor = (int*)(ws + WS_CURSOR);
    int*      bsum   = (int*)(ws + WS_BSUM);
    int*      boff   = (int*)(ws + WS_BOFF);
    unsigned* idx    = (unsigned*)(ws + WS_IDX);

    gates_kernel<<<dim3(512), dim3(256), 0, stream>>>(input, alpha, beta, ga, gb, counts);
    hist_kernel <<<dim3(1024), dim3(256), 0, stream>>>(shortlist, counts);
    scan1_kernel<<<dim3(512), dim3(256), 0, stream>>>(counts, bsum);
    scan2_kernel<<<dim3(1),   dim3(512), 0, stream>>>(bsum, boff);
    scan3_kernel<<<dim3(512), dim3(256), 0, stream>>>(counts, boff, starts, cursor);
    fill_kernel <<<dim3(1024), dim3(256), 0, stream>>>(shortlist, cursor, idx);
    main_kernel <<<dim3(2048), dim3(256), 0, stream>>>(weight, labels, bias, ga, gb,
                                                       starts, counts, idx, out);
}